// Round 4
// baseline (170.418 us; speedup 1.0000x reference)
//
#include <hip/hip_runtime.h>
#include <math.h>

// Problem constants (from reference)
#define Bdim 32
#define Ndim 325
#define Kdim 20
#define Sdim 12      // S_IN == S_OUT == 12
#define Cdim 10
#define Hdim 48      // 4*S_OUT
#define NB   (Bdim*Ndim)                  // 10400 (b,n) pairs
#define OUT_SCALARS (NB*Cdim*Sdim)        // output_data floats, then 3 scalars
#define Tpairs (Kdim*(Kdim-1)/2)          // 190 upper-triangle pairs
#define BN_BLOCKS (NB/4)                  // 2600 bn blocks (4 bn each)

// Workspace layout (float offsets); all blocks 16B-aligned
#define O_WH  0                           // NB*12 node features wh
#define O_HX  (O_WH + NB*Sdim)            // NB*48: hx + a1_b (bias pre-folded)
#define O_HY  (O_HX + NB*Hdim)            // NB*48: hy
#define O_PCL (O_HY + NB*Hdim)            // BN_BLOCKS per-block cluster-loss partials
#define O_PDS (O_PCL + BN_BLOCKS)         // BN_BLOCKS per-block dist-sum partials
#define O_PWH (O_PDS + BN_BLOCKS)         // NB per-node wh-sum partials
#define O_CNT (O_PWH + NB)                // 1 uint completion counter
#define WS_BASE_FLOATS (O_CNT + 4)

__device__ __forceinline__ float leaky(float x) { return x >= 0.f ? x : 0.5f * x; }

// ---------------------------------------------------------------------------
// K1: per-node wh, hx(+b1), hy + wh-sum partial.  4 nodes per 256-thread block
// Also zeroes K2's completion counter (stream-ordered before K2).
// ---------------------------------------------------------------------------
__global__ __launch_bounds__(256)
void node_kernel(const float* __restrict__ x,
                 const float* __restrict__ wW, const float* __restrict__ wb,
                 const float* __restrict__ A1, const float* __restrict__ b1,
                 float* __restrict__ ws)
{
    __shared__ float s_wh[4][Sdim];
    const int slot = threadIdx.x >> 6, lane = threadIdx.x & 63;
    const int node = blockIdx.x * 4 + slot;
    const float* xr = x + (size_t)node * Sdim;

    if (blockIdx.x == 0 && threadIdx.x == 0)
        *(unsigned int*)(ws + O_CNT) = 0u;

    float v = 0.f;
    if (lane < Sdim) {
        float acc = wb[lane];
        #pragma unroll
        for (int i = 0; i < Sdim; i++) acc += xr[i] * wW[i * Sdim + lane];
        v = leaky(acc);
        s_wh[slot][lane] = v;
        ws[O_WH + (size_t)node * Sdim + lane] = v;
    }
    __syncthreads();

    #pragma unroll
    for (int rep = 0; rep < 2; rep++) {
        const int e = lane + rep * 64;
        if (e < 2 * Hdim) {
            const int which = e / Hdim, d = e - which * Hdim;
            float acc = which ? 0.f : b1[d];          // fold a1_b into hx
            #pragma unroll
            for (int s = 0; s < Sdim; s++)
                acc += s_wh[slot][s] * A1[(which * Sdim + s) * Hdim + d];
            ws[(which ? O_HY : O_HX) + (size_t)node * Hdim + d] = acc;
        }
    }

    #pragma unroll
    for (int off = 32; off > 0; off >>= 1) v += __shfl_down(v, off);
    if (lane == 0) ws[O_PWH + node] = v;
}

// ---------------------------------------------------------------------------
// K2: 4 bn per 256-thread block (1 wave each). A2/b2 staged once per block.
// Att logits in-register (2 lanes/k) + in-register softmax; wtn on lanes
// 40..59; float4 einsum; 190-pair symmetric loss. Last block reduces all
// partials and writes the 3 output scalars (no third dispatch).
// ---------------------------------------------------------------------------
__global__ __launch_bounds__(256)
void bn_kernel(const int* __restrict__ topk,
               const float* __restrict__ A2, const float* __restrict__ b2,
               float* __restrict__ ws, float* __restrict__ out)
{
    __shared__ float s_A2[Hdim][12];        // c padded 10->12 with zeros
    __shared__ float s_b2[Cdim];
    __shared__ float s_hxb[4][Hdim];
    __shared__ float s_whj[4][Kdim][12];    // 48B rows, float4-aligned
    __shared__ float s_wtn[4][Kdim][12];
    __shared__ float s_am [4][Kdim][12];    // c padded with zeros (float4 dot)
    __shared__ int   s_idx[4][Kdim];
    __shared__ float s_red[2][4];
    __shared__ int   s_last;

    const int tid = threadIdx.x;
    const int slot = tid >> 6, t = tid & 63;
    const int bn = blockIdx.x * 4 + slot, b = bn / Ndim;

    // block-shared weight staging
    for (int i = tid; i < Hdim * 12; i += 256) {
        const int d = i / 12, c = i - d * 12;
        s_A2[d][c] = (c < Cdim) ? A2[d * Cdim + c] : 0.f;
    }
    if (tid < Cdim) s_b2[tid] = b2[tid];

    // per-slot staging
    if (t < Kdim) s_idx[slot][t] = topk[(size_t)bn * Kdim + t];
    if (t < Hdim) s_hxb[slot][t] = ws[O_HX + (size_t)bn * Hdim + t];
    __syncthreads();

    // gather wh_topk rows (3 float4 per row)
    if (t < Kdim * 3) {
        const int k = t / 3, q = t - k * 3;
        const float4 v = *(const float4*)(ws + O_WH + ((size_t)b * Ndim + s_idx[slot][k]) * Sdim + q * 4);
        *(float4*)&s_whj[slot][k][q * 4] = v;
    }
    __syncthreads();

    float cl = 0.f, ds = 0.f;

    if (t < 2 * Kdim) {
        // attention logits: lane pair (k, half), 24 d's each, combine via shfl_xor
        const int k = t >> 1, half = t & 1;
        const float4* hy4 = (const float4*)(ws + O_HY + ((size_t)b * Ndim + s_idx[slot][k]) * Hdim) + half * 6;
        float acc[Cdim];
        #pragma unroll
        for (int c = 0; c < Cdim; c++) acc[c] = 0.f;
        #pragma unroll
        for (int q = 0; q < 6; q++) {
            const float4 hv = hy4[q];
            const float hvv[4] = { hv.x, hv.y, hv.z, hv.w };
            #pragma unroll
            for (int i = 0; i < 4; i++) {
                const int d = half * 24 + q * 4 + i;
                const float h = leaky(s_hxb[slot][d] + hvv[i]);
                #pragma unroll
                for (int c = 0; c < Cdim; c++) acc[c] += h * s_A2[d][c];
            }
        }
        float full[Cdim];
        #pragma unroll
        for (int c = 0; c < Cdim; c++) full[c] = acc[c] + __shfl_xor(acc[c], 1);
        if (half == 0) {
            float m = -1e30f;
            #pragma unroll
            for (int c = 0; c < Cdim; c++) { full[c] = leaky(full[c] + s_b2[c]); m = fmaxf(m, full[c]); }
            float sum = 0.f;
            #pragma unroll
            for (int c = 0; c < Cdim; c++) { full[c] = __expf(full[c] - m); sum += full[c]; }
            const float inv = 1.f / sum;
            #pragma unroll
            for (int c = 0; c < Cdim; c++) s_am[slot][k][c] = full[c] * inv;
            s_am[slot][k][10] = 0.f; s_am[slot][k][11] = 0.f;
        }
    } else if (t < 2 * Kdim + Kdim) {
        // normalized wh_topk + diagonal dist contribution (runs alongside att)
        const int k = t - 2 * Kdim;
        const float4 w0 = *(const float4*)&s_whj[slot][k][0];
        const float4 w1 = *(const float4*)&s_whj[slot][k][4];
        const float4 w2 = *(const float4*)&s_whj[slot][k][8];
        const float nn = w0.x*w0.x + w0.y*w0.y + w0.z*w0.z + w0.w*w0.w
                       + w1.x*w1.x + w1.y*w1.y + w1.z*w1.z + w1.w*w1.w
                       + w2.x*w2.x + w2.y*w2.y + w2.z*w2.z + w2.w*w2.w;
        const float invn = 1.f / (sqrtf(nn) + 1e-8f);
        *(float4*)&s_wtn[slot][k][0] = make_float4(w0.x*invn, w0.y*invn, w0.z*invn, w0.w*invn);
        *(float4*)&s_wtn[slot][k][4] = make_float4(w1.x*invn, w1.y*invn, w1.z*invn, w1.w*invn);
        *(float4*)&s_wtn[slot][k][8] = make_float4(w2.x*invn, w2.y*invn, w2.z*invn, w2.w*invn);
        ds += nn * invn * invn;               // dist_mat diagonal term
    }
    __syncthreads();

    // output einsum: lane = (c, s-quad), 30 active lanes/slot, float4 stores
    if (t < Cdim * 3) {
        const int c = t / 3, sq = t - c * 3;
        float4 o = make_float4(0.f, 0.f, 0.f, 0.f);
        #pragma unroll
        for (int k = 0; k < Kdim; k++) {
            const float a = s_am[slot][k][c];
            const float4 w = *(const float4*)&s_whj[slot][k][sq * 4];
            o.x += a * w.x; o.y += a * w.y; o.z += a * w.z; o.w += a * w.w;
        }
        *(float4*)(out + (size_t)bn * (Cdim * Sdim) + c * Sdim + sq * 4) = o;
    }

    // loss: 190 upper-triangle pairs, doubled (dist/prob are symmetric)
    #pragma unroll
    for (int it = 0; it < 3; it++) {
        const int e = t + it * 64;
        if (e < Tpairs) {
            const int r = Tpairs - 1 - e;
            const int m = (int)((sqrtf((float)(8 * r + 1)) - 1.f) * 0.5f + 1e-4f);
            const int k = Kdim - 2 - m;
            const int l = Kdim - 1 - (r - (m * (m + 1)) / 2);

            const float4 a0 = *(const float4*)&s_wtn[slot][k][0];
            const float4 a1 = *(const float4*)&s_wtn[slot][k][4];
            const float4 a2 = *(const float4*)&s_wtn[slot][k][8];
            const float4 c0 = *(const float4*)&s_wtn[slot][l][0];
            const float4 c1 = *(const float4*)&s_wtn[slot][l][4];
            const float4 c2 = *(const float4*)&s_wtn[slot][l][8];
            const float d = a0.x*c0.x + a0.y*c0.y + a0.z*c0.z + a0.w*c0.w
                          + a1.x*c1.x + a1.y*c1.y + a1.z*c1.z + a1.w*c1.w
                          + a2.x*c2.x + a2.y*c2.y + a2.z*c2.z + a2.w*c2.w;

            const float4 p0 = *(const float4*)&s_am[slot][k][0];
            const float4 p1 = *(const float4*)&s_am[slot][k][4];
            const float4 p2 = *(const float4*)&s_am[slot][k][8];
            const float4 q0 = *(const float4*)&s_am[slot][l][0];
            const float4 q1 = *(const float4*)&s_am[slot][l][4];
            const float4 q2 = *(const float4*)&s_am[slot][l][8];
            float p = p0.x*q0.x + p0.y*q0.y + p0.z*q0.z + p0.w*q0.w
                    + p1.x*q1.x + p1.y*q1.y + p1.z*q1.z + p1.w*q1.w
                    + p2.x*q2.x + p2.y*q2.y + p2.z*q2.z + p2.w*q2.w;

            p = fminf(fmaxf(p, 1e-4f), 1.f - 1e-4f);
            const float lp = __logf(p);
            ds += 2.f * d;
            cl += 2.f * ((d >= 0.5f) ? -lp : lp);
        }
    }

    // wave reduce, then cross-slot reduce -> one block partial
    #pragma unroll
    for (int off = 32; off > 0; off >>= 1) {
        cl += __shfl_down(cl, off);
        ds += __shfl_down(ds, off);
    }
    if (t == 0) { s_red[0][slot] = cl; s_red[1][slot] = ds; }
    __syncthreads();
    if (tid == 0) {
        ws[O_PCL + blockIdx.x] = s_red[0][0] + s_red[0][1] + s_red[0][2] + s_red[0][3];
        ws[O_PDS + blockIdx.x] = s_red[1][0] + s_red[1][1] + s_red[1][2] + s_red[1][3];
        __threadfence();                       // release block partial
        const unsigned old = atomicAdd((unsigned int*)(ws + O_CNT), 1u);
        s_last = (old == (unsigned)(gridDim.x - 1));
    }
    __syncthreads();

    if (s_last) {
        __threadfence();                       // acquire other blocks' partials
        float fcl = 0.f, fds = 0.f, fwm = 0.f;
        for (int i = tid; i < BN_BLOCKS; i += 256) { fcl += ws[O_PCL + i]; fds += ws[O_PDS + i]; }
        for (int i = tid; i < NB; i += 256) fwm += ws[O_PWH + i];
        #pragma unroll
        for (int off = 32; off > 0; off >>= 1) {
            fcl += __shfl_down(fcl, off);
            fds += __shfl_down(fds, off);
            fwm += __shfl_down(fwm, off);
        }
        __shared__ float fr[3][4];
        if (t == 0) { fr[0][slot] = fcl; fr[1][slot] = fds; fr[2][slot] = fwm; }
        __syncthreads();
        if (tid == 0) {
            const float c = fr[0][0] + fr[0][1] + fr[0][2] + fr[0][3];
            const float d = fr[1][0] + fr[1][1] + fr[1][2] + fr[1][3];
            const float m = fr[2][0] + fr[2][1] + fr[2][2] + fr[2][3];
            out[OUT_SCALARS + 0] = c * (1.f / (float)NB);
            out[OUT_SCALARS + 1] = d * (1.f / ((float)NB * Kdim * Kdim));
            out[OUT_SCALARS + 2] = m * (1.f / ((float)NB * Sdim));
        }
    }
}

// ---------------------------------------------------------------------------
// Fallback: round-1 monolithic kernel (used only if ws is too small)
// ---------------------------------------------------------------------------
__global__ void zero_scalars(float* out) {
    const int t = threadIdx.x;
    if (t < 3) out[OUT_SCALARS + t] = 0.f;
}

__global__ __launch_bounds__(64)
void fused_kernel(const float* __restrict__ input_data,
                  const float* __restrict__ w_W,  const float* __restrict__ w_b,
                  const float* __restrict__ a1_W, const float* __restrict__ a1_b,
                  const float* __restrict__ a2_W, const float* __restrict__ a2_b,
                  const int*   __restrict__ topk,
                  float* __restrict__ out)
{
    __shared__ float s_wW[Sdim * Sdim];
    __shared__ float s_wb[Sdim];
    __shared__ float s_A1[2 * Sdim * Hdim];
    __shared__ float s_b1[Hdim];
    __shared__ float s_A2f[Hdim * Cdim];
    __shared__ float s_b2f[Cdim];
    __shared__ float s_whs[Sdim];
    __shared__ float s_hx[Hdim];
    __shared__ float s_whj[Kdim][Sdim + 1];
    __shared__ float s_hid[Kdim][Hdim + 1];
    __shared__ float s_am [Kdim][Cdim + 1];
    __shared__ float s_wtn[Kdim][Sdim + 1];
    __shared__ int   s_idx[Kdim];

    const int t = threadIdx.x, bn = blockIdx.x, b = bn / Ndim;

    for (int i = t; i < Sdim * Sdim; i += 64)      s_wW[i] = w_W[i];
    if (t < Sdim)                                  s_wb[t] = w_b[t];
    for (int i = t; i < 2 * Sdim * Hdim; i += 64)  s_A1[i] = a1_W[i];
    if (t < Hdim)                                  s_b1[t] = a1_b[t];
    for (int i = t; i < Hdim * Cdim; i += 64)      s_A2f[i] = a2_W[i];
    if (t < Cdim)                                  s_b2f[t] = a2_b[t];
    if (t < Kdim)                                  s_idx[t] = topk[(size_t)bn * Kdim + t];
    __syncthreads();

    const float* xs = input_data + (size_t)bn * Sdim;
    if (t < Sdim) {
        float acc = s_wb[t];
        #pragma unroll
        for (int i = 0; i < Sdim; i++) acc += xs[i] * s_wW[i * Sdim + t];
        s_whs[t] = leaky(acc);
    }
    __syncthreads();

    if (t < Hdim) {
        float acc = 0.f;
        #pragma unroll
        for (int s = 0; s < Sdim; s++) acc += s_whs[s] * s_A1[s * Hdim + t];
        s_hx[t] = acc;
    }
    for (int e = t; e < Kdim * Sdim; e += 64) {
        const int k = e / Sdim, ss = e - k * Sdim;
        const float* xj = input_data + ((size_t)b * Ndim + s_idx[k]) * Sdim;
        float acc = s_wb[ss];
        #pragma unroll
        for (int i = 0; i < Sdim; i++) acc += xj[i] * s_wW[i * Sdim + ss];
        s_whj[k][ss] = leaky(acc);
    }
    __syncthreads();

    for (int e = t; e < Kdim * Hdim; e += 64) {
        const int k = e / Hdim, d = e - k * Hdim;
        float acc = s_hx[d] + s_b1[d];
        #pragma unroll
        for (int s = 0; s < Sdim; s++) acc += s_whj[k][s] * s_A1[(Sdim + s) * Hdim + d];
        s_hid[k][d] = leaky(acc);
    }
    __syncthreads();

    for (int e = t; e < Kdim * Cdim; e += 64) {
        const int k = e / Cdim, c = e - k * Cdim;
        float acc = s_b2f[c];
        #pragma unroll
        for (int d = 0; d < Hdim; d++) acc += s_hid[k][d] * s_A2f[d * Cdim + c];
        s_am[k][c] = leaky(acc);
    }
    __syncthreads();

    if (t < Kdim) {
        float m = -1e30f;
        #pragma unroll
        for (int c = 0; c < Cdim; c++) m = fmaxf(m, s_am[t][c]);
        float ex[Cdim]; float sum = 0.f;
        #pragma unroll
        for (int c = 0; c < Cdim; c++) { ex[c] = expf(s_am[t][c] - m); sum += ex[c]; }
        const float inv = 1.f / sum;
        #pragma unroll
        for (int c = 0; c < Cdim; c++) s_am[t][c] = ex[c] * inv;
        float nn = 0.f;
        #pragma unroll
        for (int s = 0; s < Sdim; s++) nn += s_whj[t][s] * s_whj[t][s];
        const float invn = 1.f / (sqrtf(nn) + 1e-8f);
        #pragma unroll
        for (int s = 0; s < Sdim; s++) s_wtn[t][s] = s_whj[t][s] * invn;
    }
    __syncthreads();

    float* op = out + (size_t)bn * (Cdim * Sdim);
    for (int e = t; e < Cdim * Sdim; e += 64) {
        const int c = e / Sdim, ss = e - c * Sdim;
        float acc = 0.f;
        #pragma unroll
        for (int k = 0; k < Kdim; k++) acc += s_am[k][c] * s_whj[k][ss];
        op[e] = acc;
    }

    float cl = 0.f, ds = 0.f;
    for (int e = t; e < Kdim * Kdim; e += 64) {
        const int k = e / Kdim, l = e - k * Kdim;
        float d = 0.f;
        #pragma unroll
        for (int s = 0; s < Sdim; s++) d += s_wtn[k][s] * s_wtn[l][s];
        ds += d;
        if (k != l) {
            float p = 0.f;
            #pragma unroll
            for (int c = 0; c < Cdim; c++) p += s_am[k][c] * s_am[l][c];
            p = fminf(fmaxf(p, 1e-4f), 1.f - 1e-4f);
            const float lp = logf(p);
            cl += (d >= 0.5f) ? -lp : lp;
        }
    }
    float whl = (t < Sdim) ? s_whs[t] : 0.f;
    #pragma unroll
    for (int off = 32; off > 0; off >>= 1) {
        cl  += __shfl_down(cl,  off);
        ds  += __shfl_down(ds,  off);
        whl += __shfl_down(whl, off);
    }
    if (t == 0) {
        atomicAdd(&out[OUT_SCALARS + 0], cl  * (1.f / (float)NB));
        atomicAdd(&out[OUT_SCALARS + 1], ds  * (1.f / ((float)NB * Kdim * Kdim)));
        atomicAdd(&out[OUT_SCALARS + 2], whl * (1.f / ((float)NB * Sdim)));
    }
}

extern "C" void kernel_launch(void* const* d_in, const int* in_sizes, int n_in,
                              void* d_out, int out_size, void* d_ws, size_t ws_size,
                              hipStream_t stream) {
    (void)in_sizes; (void)n_in; (void)out_size;
    // 0=fushed_features(unused), 1=input_data, 2=w_W, 3=w_b, 4=a1_W, 5=a1_b,
    // 6=a2_W, 7=a2_b, 8=adj_mx_topk_index
    const float* input_data = (const float*)d_in[1];
    const float* w_W  = (const float*)d_in[2];
    const float* w_b  = (const float*)d_in[3];
    const float* a1_W = (const float*)d_in[4];
    const float* a1_b = (const float*)d_in[5];
    const float* a2_W = (const float*)d_in[6];
    const float* a2_b = (const float*)d_in[7];
    const int*   topk = (const int*)d_in[8];
    float* out = (float*)d_out;
    float* ws  = (float*)d_ws;

    if (ws_size >= (size_t)WS_BASE_FLOATS * sizeof(float)) {
        hipLaunchKernelGGL(node_kernel, dim3(NB / 4), dim3(256), 0, stream,
                           input_data, w_W, w_b, a1_W, a1_b, ws);
        hipLaunchKernelGGL(bn_kernel, dim3(BN_BLOCKS), dim3(256), 0, stream,
                           topk, a2_W, a2_b, ws, out);
    } else {
        hipLaunchKernelGGL(zero_scalars, dim3(1), dim3(64), 0, stream, out);
        hipLaunchKernelGGL(fused_kernel, dim3(NB), dim3(64), 0, stream,
                           input_data, w_W, w_b, a1_W, a1_b, a2_W, a2_b, topk, out);
    }
}

// Round 5
// 110.091 us; speedup vs baseline: 1.5480x; 1.5480x over previous
//
#include <hip/hip_runtime.h>
#include <math.h>

// Problem constants (from reference)
#define Bdim 32
#define Ndim 325
#define Kdim 20
#define Sdim 12      // S_IN == S_OUT == 12
#define Cdim 10
#define Hdim 48      // 4*S_OUT
#define NB   (Bdim*Ndim)                  // 10400 (b,n) pairs
#define OUT_SCALARS (NB*Cdim*Sdim)        // output_data floats, then 3 scalars
#define Tpairs (Kdim*(Kdim-1)/2)          // 190 upper-triangle pairs
#define BN_BLOCKS (NB/4)                  // 2600 bn blocks (4 bn each)

// Workspace layout (float offsets); all blocks 16B-aligned
#define O_WH  0                           // NB*12 node features wh
#define O_HX  (O_WH + NB*Sdim)            // NB*48: hx + a1_b (bias pre-folded)
#define O_HY  (O_HX + NB*Hdim)            // NB*48: hy
#define O_PCL (O_HY + NB*Hdim)            // BN_BLOCKS per-block cluster-loss partials
#define O_PDS (O_PCL + BN_BLOCKS)         // BN_BLOCKS per-block dist-sum partials
#define O_PWH (O_PDS + BN_BLOCKS)         // NB per-node wh-sum partials
#define WS_BASE_FLOATS (O_PWH + NB)

__device__ __forceinline__ float leaky(float x) { return x >= 0.f ? x : 0.5f * x; }

// ---------------------------------------------------------------------------
// K1: per-node wh, hx(+b1), hy + wh-sum partial.  4 nodes per 256-thread block
// ---------------------------------------------------------------------------
__global__ __launch_bounds__(256)
void node_kernel(const float* __restrict__ x,
                 const float* __restrict__ wW, const float* __restrict__ wb,
                 const float* __restrict__ A1, const float* __restrict__ b1,
                 float* __restrict__ ws)
{
    __shared__ float s_wh[4][Sdim];
    const int slot = threadIdx.x >> 6, lane = threadIdx.x & 63;
    const int node = blockIdx.x * 4 + slot;
    const float* xr = x + (size_t)node * Sdim;

    float v = 0.f;
    if (lane < Sdim) {
        float acc = wb[lane];
        #pragma unroll
        for (int i = 0; i < Sdim; i++) acc += xr[i] * wW[i * Sdim + lane];
        v = leaky(acc);
        s_wh[slot][lane] = v;
        ws[O_WH + (size_t)node * Sdim + lane] = v;
    }
    __syncthreads();

    #pragma unroll
    for (int rep = 0; rep < 2; rep++) {
        const int e = lane + rep * 64;
        if (e < 2 * Hdim) {
            const int which = e / Hdim, d = e - which * Hdim;
            float acc = which ? 0.f : b1[d];          // fold a1_b into hx
            #pragma unroll
            for (int s = 0; s < Sdim; s++)
                acc += s_wh[slot][s] * A1[(which * Sdim + s) * Hdim + d];
            ws[(which ? O_HY : O_HX) + (size_t)node * Hdim + d] = acc;
        }
    }

    #pragma unroll
    for (int off = 32; off > 0; off >>= 1) v += __shfl_down(v, off);
    if (lane == 0) ws[O_PWH + node] = v;
}

// ---------------------------------------------------------------------------
// K2: 4 bn per 256-thread block (1 wave each). A2/b2 staged once per block.
// Att logits in-register (2 lanes/k) + in-register softmax; wtn on lanes
// 40..59; float4 einsum; 190-pair symmetric loss. Per-BLOCK partials to ws.
// NO device fences / global atomics (R4 post-mortem: ~40+ us regression).
// ---------------------------------------------------------------------------
__global__ __launch_bounds__(256)
void bn_kernel(const int* __restrict__ topk,
               const float* __restrict__ A2, const float* __restrict__ b2,
               float* __restrict__ ws, float* __restrict__ out)
{
    __shared__ float s_A2[Hdim][12];        // c padded 10->12 with zeros
    __shared__ float s_b2[Cdim];
    __shared__ float s_hxb[4][Hdim];
    __shared__ float s_whj[4][Kdim][12];    // 48B rows, float4-aligned
    __shared__ float s_wtn[4][Kdim][12];
    __shared__ float s_am [4][Kdim][12];    // c padded with zeros (float4 dot)
    __shared__ int   s_idx[4][Kdim];
    __shared__ float s_red[2][4];

    const int tid = threadIdx.x;
    const int slot = tid >> 6, t = tid & 63;
    const int bn = blockIdx.x * 4 + slot, b = bn / Ndim;

    // block-shared weight staging
    for (int i = tid; i < Hdim * 12; i += 256) {
        const int d = i / 12, c = i - d * 12;
        s_A2[d][c] = (c < Cdim) ? A2[d * Cdim + c] : 0.f;
    }
    if (tid < Cdim) s_b2[tid] = b2[tid];

    // per-slot staging
    if (t < Kdim) s_idx[slot][t] = topk[(size_t)bn * Kdim + t];
    if (t < Hdim) s_hxb[slot][t] = ws[O_HX + (size_t)bn * Hdim + t];
    __syncthreads();

    // gather wh_topk rows (3 float4 per row)
    if (t < Kdim * 3) {
        const int k = t / 3, q = t - k * 3;
        const float4 v = *(const float4*)(ws + O_WH + ((size_t)b * Ndim + s_idx[slot][k]) * Sdim + q * 4);
        *(float4*)&s_whj[slot][k][q * 4] = v;
    }
    __syncthreads();

    float cl = 0.f, ds = 0.f;

    if (t < 2 * Kdim) {
        // attention logits: lane pair (k, half), 24 d's each, combine via shfl_xor
        const int k = t >> 1, half = t & 1;
        const float4* hy4 = (const float4*)(ws + O_HY + ((size_t)b * Ndim + s_idx[slot][k]) * Hdim) + half * 6;
        float acc[Cdim];
        #pragma unroll
        for (int c = 0; c < Cdim; c++) acc[c] = 0.f;
        #pragma unroll
        for (int q = 0; q < 6; q++) {
            const float4 hv = hy4[q];
            const float hvv[4] = { hv.x, hv.y, hv.z, hv.w };
            #pragma unroll
            for (int i = 0; i < 4; i++) {
                const int d = half * 24 + q * 4 + i;
                const float h = leaky(s_hxb[slot][d] + hvv[i]);
                #pragma unroll
                for (int c = 0; c < Cdim; c++) acc[c] += h * s_A2[d][c];
            }
        }
        float full[Cdim];
        #pragma unroll
        for (int c = 0; c < Cdim; c++) full[c] = acc[c] + __shfl_xor(acc[c], 1);
        if (half == 0) {
            float m = -1e30f;
            #pragma unroll
            for (int c = 0; c < Cdim; c++) { full[c] = leaky(full[c] + s_b2[c]); m = fmaxf(m, full[c]); }
            float sum = 0.f;
            #pragma unroll
            for (int c = 0; c < Cdim; c++) { full[c] = __expf(full[c] - m); sum += full[c]; }
            const float inv = 1.f / sum;
            #pragma unroll
            for (int c = 0; c < Cdim; c++) s_am[slot][k][c] = full[c] * inv;
            s_am[slot][k][10] = 0.f; s_am[slot][k][11] = 0.f;
        }
    } else if (t < 2 * Kdim + Kdim) {
        // normalized wh_topk + diagonal dist contribution (runs alongside att)
        const int k = t - 2 * Kdim;
        const float4 w0 = *(const float4*)&s_whj[slot][k][0];
        const float4 w1 = *(const float4*)&s_whj[slot][k][4];
        const float4 w2 = *(const float4*)&s_whj[slot][k][8];
        const float nn = w0.x*w0.x + w0.y*w0.y + w0.z*w0.z + w0.w*w0.w
                       + w1.x*w1.x + w1.y*w1.y + w1.z*w1.z + w1.w*w1.w
                       + w2.x*w2.x + w2.y*w2.y + w2.z*w2.z + w2.w*w2.w;
        const float invn = 1.f / (sqrtf(nn) + 1e-8f);
        *(float4*)&s_wtn[slot][k][0] = make_float4(w0.x*invn, w0.y*invn, w0.z*invn, w0.w*invn);
        *(float4*)&s_wtn[slot][k][4] = make_float4(w1.x*invn, w1.y*invn, w1.z*invn, w1.w*invn);
        *(float4*)&s_wtn[slot][k][8] = make_float4(w2.x*invn, w2.y*invn, w2.z*invn, w2.w*invn);
        ds += nn * invn * invn;               // dist_mat diagonal term
    }
    __syncthreads();

    // output einsum: lane = (c, s-quad), 30 active lanes/slot, float4 stores
    if (t < Cdim * 3) {
        const int c = t / 3, sq = t - c * 3;
        float4 o = make_float4(0.f, 0.f, 0.f, 0.f);
        #pragma unroll
        for (int k = 0; k < Kdim; k++) {
            const float a = s_am[slot][k][c];
            const float4 w = *(const float4*)&s_whj[slot][k][sq * 4];
            o.x += a * w.x; o.y += a * w.y; o.z += a * w.z; o.w += a * w.w;
        }
        *(float4*)(out + (size_t)bn * (Cdim * Sdim) + c * Sdim + sq * 4) = o;
    }

    // loss: 190 upper-triangle pairs, doubled (dist/prob are symmetric)
    #pragma unroll
    for (int it = 0; it < 3; it++) {
        const int e = t + it * 64;
        if (e < Tpairs) {
            const int r = Tpairs - 1 - e;
            const int m = (int)((sqrtf((float)(8 * r + 1)) - 1.f) * 0.5f + 1e-4f);
            const int k = Kdim - 2 - m;
            const int l = Kdim - 1 - (r - (m * (m + 1)) / 2);

            const float4 a0 = *(const float4*)&s_wtn[slot][k][0];
            const float4 a1 = *(const float4*)&s_wtn[slot][k][4];
            const float4 a2 = *(const float4*)&s_wtn[slot][k][8];
            const float4 c0 = *(const float4*)&s_wtn[slot][l][0];
            const float4 c1 = *(const float4*)&s_wtn[slot][l][4];
            const float4 c2 = *(const float4*)&s_wtn[slot][l][8];
            const float d = a0.x*c0.x + a0.y*c0.y + a0.z*c0.z + a0.w*c0.w
                          + a1.x*c1.x + a1.y*c1.y + a1.z*c1.z + a1.w*c1.w
                          + a2.x*c2.x + a2.y*c2.y + a2.z*c2.z + a2.w*c2.w;

            const float4 p0 = *(const float4*)&s_am[slot][k][0];
            const float4 p1 = *(const float4*)&s_am[slot][k][4];
            const float4 p2 = *(const float4*)&s_am[slot][k][8];
            const float4 q0 = *(const float4*)&s_am[slot][l][0];
            const float4 q1 = *(const float4*)&s_am[slot][l][4];
            const float4 q2 = *(const float4*)&s_am[slot][l][8];
            float p = p0.x*q0.x + p0.y*q0.y + p0.z*q0.z + p0.w*q0.w
                    + p1.x*q1.x + p1.y*q1.y + p1.z*q1.z + p1.w*q1.w
                    + p2.x*q2.x + p2.y*q2.y + p2.z*q2.z + p2.w*q2.w;

            p = fminf(fmaxf(p, 1e-4f), 1.f - 1e-4f);
            const float lp = __logf(p);
            ds += 2.f * d;
            cl += 2.f * ((d >= 0.5f) ? -lp : lp);
        }
    }

    // wave reduce, then cross-slot reduce -> one block partial (plain stores)
    #pragma unroll
    for (int off = 32; off > 0; off >>= 1) {
        cl += __shfl_down(cl, off);
        ds += __shfl_down(ds, off);
    }
    if (t == 0) { s_red[0][slot] = cl; s_red[1][slot] = ds; }
    __syncthreads();
    if (tid == 0) {
        ws[O_PCL + blockIdx.x] = s_red[0][0] + s_red[0][1] + s_red[0][2] + s_red[0][3];
        ws[O_PDS + blockIdx.x] = s_red[1][0] + s_red[1][1] + s_red[1][2] + s_red[1][3];
    }
}

// ---------------------------------------------------------------------------
// K3: reduce partials -> 3 output scalars (tiny; ~3 us incl. launch gap)
// ---------------------------------------------------------------------------
__global__ __launch_bounds__(1024)
void finalize(const float* __restrict__ ws, float* __restrict__ out)
{
    const int t = threadIdx.x;
    float cl = 0.f, ds = 0.f, wm = 0.f;
    for (int i = t; i < BN_BLOCKS; i += 1024) {
        cl += ws[O_PCL + i]; ds += ws[O_PDS + i];
    }
    for (int i = t; i < NB; i += 1024) wm += ws[O_PWH + i];
    #pragma unroll
    for (int off = 32; off > 0; off >>= 1) {
        cl += __shfl_down(cl, off);
        ds += __shfl_down(ds, off);
        wm += __shfl_down(wm, off);
    }
    __shared__ float r[3][16];
    const int w = t >> 6, lane = t & 63;
    if (lane == 0) { r[0][w] = cl; r[1][w] = ds; r[2][w] = wm; }
    __syncthreads();
    if (t == 0) {
        float c = 0.f, d = 0.f, m = 0.f;
        #pragma unroll
        for (int i = 0; i < 16; i++) { c += r[0][i]; d += r[1][i]; m += r[2][i]; }
        out[OUT_SCALARS + 0] = c * (1.f / (float)NB);
        out[OUT_SCALARS + 1] = d * (1.f / ((float)NB * Kdim * Kdim));
        out[OUT_SCALARS + 2] = m * (1.f / ((float)NB * Sdim));
    }
}

// ---------------------------------------------------------------------------
// Fallback: round-1 monolithic kernel (used only if ws is too small)
// ---------------------------------------------------------------------------
__global__ void zero_scalars(float* out) {
    const int t = threadIdx.x;
    if (t < 3) out[OUT_SCALARS + t] = 0.f;
}

__global__ __launch_bounds__(64)
void fused_kernel(const float* __restrict__ input_data,
                  const float* __restrict__ w_W,  const float* __restrict__ w_b,
                  const float* __restrict__ a1_W, const float* __restrict__ a1_b,
                  const float* __restrict__ a2_W, const float* __restrict__ a2_b,
                  const int*   __restrict__ topk,
                  float* __restrict__ out)
{
    __shared__ float s_wW[Sdim * Sdim];
    __shared__ float s_wb[Sdim];
    __shared__ float s_A1[2 * Sdim * Hdim];
    __shared__ float s_b1[Hdim];
    __shared__ float s_A2f[Hdim * Cdim];
    __shared__ float s_b2f[Cdim];
    __shared__ float s_whs[Sdim];
    __shared__ float s_hx[Hdim];
    __shared__ float s_whj[Kdim][Sdim + 1];
    __shared__ float s_hid[Kdim][Hdim + 1];
    __shared__ float s_am [Kdim][Cdim + 1];
    __shared__ float s_wtn[Kdim][Sdim + 1];
    __shared__ int   s_idx[Kdim];

    const int t = threadIdx.x, bn = blockIdx.x, b = bn / Ndim;

    for (int i = t; i < Sdim * Sdim; i += 64)      s_wW[i] = w_W[i];
    if (t < Sdim)                                  s_wb[t] = w_b[t];
    for (int i = t; i < 2 * Sdim * Hdim; i += 64)  s_A1[i] = a1_W[i];
    if (t < Hdim)                                  s_b1[t] = a1_b[t];
    for (int i = t; i < Hdim * Cdim; i += 64)      s_A2f[i] = a2_W[i];
    if (t < Cdim)                                  s_b2f[t] = a2_b[t];
    if (t < Kdim)                                  s_idx[t] = topk[(size_t)bn * Kdim + t];
    __syncthreads();

    const float* xs = input_data + (size_t)bn * Sdim;
    if (t < Sdim) {
        float acc = s_wb[t];
        #pragma unroll
        for (int i = 0; i < Sdim; i++) acc += xs[i] * s_wW[i * Sdim + t];
        s_whs[t] = leaky(acc);
    }
    __syncthreads();

    if (t < Hdim) {
        float acc = 0.f;
        #pragma unroll
        for (int s = 0; s < Sdim; s++) acc += s_whs[s] * s_A1[s * Hdim + t];
        s_hx[t] = acc;
    }
    for (int e = t; e < Kdim * Sdim; e += 64) {
        const int k = e / Sdim, ss = e - k * Sdim;
        const float* xj = input_data + ((size_t)b * Ndim + s_idx[k]) * Sdim;
        float acc = s_wb[ss];
        #pragma unroll
        for (int i = 0; i < Sdim; i++) acc += xj[i] * s_wW[i * Sdim + ss];
        s_whj[k][ss] = leaky(acc);
    }
    __syncthreads();

    for (int e = t; e < Kdim * Hdim; e += 64) {
        const int k = e / Hdim, d = e - k * Hdim;
        float acc = s_hx[d] + s_b1[d];
        #pragma unroll
        for (int s = 0; s < Sdim; s++) acc += s_whj[k][s] * s_A1[(Sdim + s) * Hdim + d];
        s_hid[k][d] = leaky(acc);
    }
    __syncthreads();

    for (int e = t; e < Kdim * Cdim; e += 64) {
        const int k = e / Cdim, c = e - k * Cdim;
        float acc = s_b2f[c];
        #pragma unroll
        for (int d = 0; d < Hdim; d++) acc += s_hid[k][d] * s_A2f[d * Cdim + c];
        s_am[k][c] = leaky(acc);
    }
    __syncthreads();

    if (t < Kdim) {
        float m = -1e30f;
        #pragma unroll
        for (int c = 0; c < Cdim; c++) m = fmaxf(m, s_am[t][c]);
        float ex[Cdim]; float sum = 0.f;
        #pragma unroll
        for (int c = 0; c < Cdim; c++) { ex[c] = expf(s_am[t][c] - m); sum += ex[c]; }
        const float inv = 1.f / sum;
        #pragma unroll
        for (int c = 0; c < Cdim; c++) s_am[t][c] = ex[c] * inv;
        float nn = 0.f;
        #pragma unroll
        for (int s = 0; s < Sdim; s++) nn += s_whj[t][s] * s_whj[t][s];
        const float invn = 1.f / (sqrtf(nn) + 1e-8f);
        #pragma unroll
        for (int s = 0; s < Sdim; s++) s_wtn[t][s] = s_whj[t][s] * invn;
    }
    __syncthreads();

    float* op = out + (size_t)bn * (Cdim * Sdim);
    for (int e = t; e < Cdim * Sdim; e += 64) {
        const int c = e / Sdim, ss = e - c * Sdim;
        float acc = 0.f;
        #pragma unroll
        for (int k = 0; k < Kdim; k++) acc += s_am[k][c] * s_whj[k][ss];
        op[e] = acc;
    }

    float cl = 0.f, ds = 0.f;
    for (int e = t; e < Kdim * Kdim; e += 64) {
        const int k = e / Kdim, l = e - k * Kdim;
        float d = 0.f;
        #pragma unroll
        for (int s = 0; s < Sdim; s++) d += s_wtn[k][s] * s_wtn[l][s];
        ds += d;
        if (k != l) {
            float p = 0.f;
            #pragma unroll
            for (int c = 0; c < Cdim; c++) p += s_am[k][c] * s_am[l][c];
            p = fminf(fmaxf(p, 1e-4f), 1.f - 1e-4f);
            const float lp = logf(p);
            cl += (d >= 0.5f) ? -lp : lp;
        }
    }
    float whl = (t < Sdim) ? s_whs[t] : 0.f;
    #pragma unroll
    for (int off = 32; off > 0; off >>= 1) {
        cl  += __shfl_down(cl,  off);
        ds  += __shfl_down(ds,  off);
        whl += __shfl_down(whl, off);
    }
    if (t == 0) {
        atomicAdd(&out[OUT_SCALARS + 0], cl  * (1.f / (float)NB));
        atomicAdd(&out[OUT_SCALARS + 1], ds  * (1.f / ((float)NB * Kdim * Kdim)));
        atomicAdd(&out[OUT_SCALARS + 2], whl * (1.f / ((float)NB * Sdim)));
    }
}

extern "C" void kernel_launch(void* const* d_in, const int* in_sizes, int n_in,
                              void* d_out, int out_size, void* d_ws, size_t ws_size,
                              hipStream_t stream) {
    (void)in_sizes; (void)n_in; (void)out_size;
    // 0=fushed_features(unused), 1=input_data, 2=w_W, 3=w_b, 4=a1_W, 5=a1_b,
    // 6=a2_W, 7=a2_b, 8=adj_mx_topk_index
    const float* input_data = (const float*)d_in[1];
    const float* w_W  = (const float*)d_in[2];
    const float* w_b  = (const float*)d_in[3];
    const float* a1_W = (const float*)d_in[4];
    const float* a1_b = (const float*)d_in[5];
    const float* a2_W = (const float*)d_in[6];
    const float* a2_b = (const float*)d_in[7];
    const int*   topk = (const int*)d_in[8];
    float* out = (float*)d_out;
    float* ws  = (float*)d_ws;

    if (ws_size >= (size_t)WS_BASE_FLOATS * sizeof(float)) {
        hipLaunchKernelGGL(node_kernel, dim3(NB / 4), dim3(256), 0, stream,
                           input_data, w_W, w_b, a1_W, a1_b, ws);
        hipLaunchKernelGGL(bn_kernel, dim3(BN_BLOCKS), dim3(256), 0, stream,
                           topk, a2_W, a2_b, ws, out);
        hipLaunchKernelGGL(finalize, dim3(1), dim3(1024), 0, stream, ws, out);
    } else {
        hipLaunchKernelGGL(zero_scalars, dim3(1), dim3(64), 0, stream, out);
        hipLaunchKernelGGL(fused_kernel, dim3(NB), dim3(64), 0, stream,
                           input_data, w_W, w_b, a1_W, a1_b, a2_W, a2_b, topk, out);
    }
}